// Round 1
// baseline (389.761 us; speedup 1.0000x reference)
//
#include <hip/hip_runtime.h>
#include <hip/hip_bf16.h>
#include <stdint.h>

#define TLEN 64
#define BSZ 32
#define SLEN 64
#define HS 1024
#define VOC 32000
#define NROW (TLEN*BSZ)   // 2048
#define C_CONST_F 0.1712209f

typedef __attribute__((ext_vector_type(8))) short short8;
typedef __attribute__((ext_vector_type(4))) float f32x4;

static __device__ __forceinline__ ushort f2bf(float f) {
    uint32_t u = __builtin_bit_cast(uint32_t, f);
    uint32_t r = (u + 0x7fffu + ((u >> 16) & 1u)) >> 16;
    return (ushort)r;
}

static __device__ __forceinline__ void async16(const void* g, void* lds) {
    __builtin_amdgcn_global_load_lds(
        (const __attribute__((address_space(1))) void*)g,
        (__attribute__((address_space(3))) void*)lds, 16, 0, 0);
}

// ---------------- copy gate: cp[row] = sigmoid(dot(hidden[row], w_copy) + b_copy) ----
__global__ __launch_bounds__(256) void gate_kernel(const float* __restrict__ hidden,
                                                   const float* __restrict__ w_copy,
                                                   const float* __restrict__ b_copy,
                                                   float* __restrict__ cp) {
    int wid = threadIdx.x >> 6, lane = threadIdx.x & 63;
    int row = blockIdx.x * 4 + wid;
    const float* h = hidden + (size_t)row * HS;
    float acc = 0.f;
    for (int i = 0; i < 4; ++i) {
        int off = (i * 64 + lane) * 4;
        float4 a = *(const float4*)(h + off);
        float4 w = *(const float4*)(w_copy + off);
        acc += a.x * w.x + a.y * w.y + a.z * w.z + a.w * w.w;
    }
    for (int m = 32; m >= 1; m >>= 1) acc += __shfl_xor(acc, m, 64);
    if (lane == 0) cp[row] = 1.f / (1.f + expf(-(acc + b_copy[0])));
}

// ---------------- copy attention: p_c[row][s] (f32 for precision) -------------------
__global__ __launch_bounds__(256) void attn_kernel(const float* __restrict__ hidden,
                                                   const float* __restrict__ context,
                                                   const int* __restrict__ src,
                                                   const float* __restrict__ cp,
                                                   float* __restrict__ p_c) {
    int row = blockIdx.x;           // t*BSZ + b
    int b = row & (BSZ - 1);
    int tid = threadIdx.x, wid = tid >> 6, lane = tid & 63;
    __shared__ float hrow[HS];
    __shared__ float sc[SLEN];
    *(float4*)(hrow + tid * 4) = *(const float4*)(hidden + (size_t)row * HS + tid * 4);
    __syncthreads();
    for (int j = 0; j < 16; ++j) {
        int s = wid * 16 + j;
        const float* c = context + ((size_t)s * BSZ + b) * HS;
        float acc = 0.f;
        for (int i = 0; i < 4; ++i) {
            int off = (i * 64 + lane) * 4;
            float4 cv = *(const float4*)(c + off);
            float4 hv = *(const float4*)(hrow + off);
            acc += cv.x * hv.x + cv.y * hv.y + cv.z * hv.z + cv.w * hv.w;
        }
        for (int m = 32; m >= 1; m >>= 1) acc += __shfl_xor(acc, m, 64);
        if (lane == 0) sc[s] = acc;
    }
    __syncthreads();
    if (tid < SLEN) {
        float v = sc[tid];
        if (src[b * SLEN + tid] == 0) v = -INFINITY;   // PAD mask
        float m = v;
        for (int k = 32; k >= 1; k >>= 1) m = fmaxf(m, __shfl_xor(m, k, 64));
        float e = expf(v - m);                          // exp(-inf - m) = 0
        float ssum = e;
        for (int k = 32; k >= 1; k >>= 1) ssum += __shfl_xor(ssum, k, 64);
        p_c[row * SLEN + tid] = (e / ssum) * cp[row];
    }
}

// ---------------- f32 -> bf16 conversion (vectorized) -------------------------------
__global__ __launch_bounds__(256) void cvt_kernel(const float* __restrict__ in,
                                                  ushort* __restrict__ out, int n4) {
    int i = blockIdx.x * blockDim.x + threadIdx.x;
    if (i >= n4) return;
    float4 v = ((const float4*)in)[i];
    ushort4 o;
    o.x = f2bf(v.x); o.y = f2bf(v.y); o.z = f2bf(v.z); o.w = f2bf(v.w);
    ((ushort4*)out)[i] = o;
}

// ---------------- main GEMM: logits = A(2048x1024) * B(32000x1024)^T + b_gen --------
// 128x128 tile, BK=32, 4 waves (2x2), each wave 64x64 via 4x4 frags of 16x16x32 MFMA.
// Epilogue: write logits f32 to out, emit per-64-col (max, sumexp) partials.
__global__ __launch_bounds__(256) void gemm_kernel(const ushort* __restrict__ A,
                                                   const ushort* __restrict__ B,
                                                   const float* __restrict__ b_gen,
                                                   float* __restrict__ out,
                                                   float* __restrict__ partials /*[NROW][500][2]*/) {
    __shared__ ushort sA[128 * 32];
    __shared__ ushort sB[128 * 32];
    int bid = blockIdx.x;
    int mIdx = bid & 15;          // 16 m-tiles (consecutive bids share B panel)
    int nIdx = bid >> 4;          // 250 n-tiles
    int m0 = mIdx * 128, n0 = nIdx * 128;
    int tid = threadIdx.x, wid = tid >> 6, lane = tid & 63;
    int wm = (wid >> 1) * 64, wn = (wid & 1) * 64;
    int lr = lane & 15, lg = lane >> 4;

    f32x4 acc[4][4];
    for (int m = 0; m < 4; ++m)
        for (int n = 0; n < 4; ++n)
            acc[m][n] = f32x4{0.f, 0.f, 0.f, 0.f};

    for (int k0 = 0; k0 < HS; k0 += 32) {
        // stage A,B tiles (8KB each) via global_load_lds width=16
        for (int rep = 0; rep < 2; ++rep) {
            int i = tid + 256 * rep;
            int r = i >> 2, c = (i & 3) * 8;
            const ushort* ga = A + (size_t)(m0 + r) * HS + k0 + c;
            const ushort* gb = B + (size_t)(n0 + r) * HS + k0 + c;
            char* la = (char*)sA + (size_t)(wid * 64 + 256 * rep) * 16;
            char* lb = (char*)sB + (size_t)(wid * 64 + 256 * rep) * 16;
            async16(ga, la);
            async16(gb, lb);
        }
        __syncthreads();   // compiler drains vmcnt before barrier
        short8 af[4], bf[4];
        for (int mb = 0; mb < 4; ++mb)
            af[mb] = *(const short8*)(sA + (wm + mb * 16 + lr) * 32 + lg * 8);
        for (int nb = 0; nb < 4; ++nb)
            bf[nb] = *(const short8*)(sB + (wn + nb * 16 + lr) * 32 + lg * 8);
        for (int mb = 0; mb < 4; ++mb)
            for (int nb = 0; nb < 4; ++nb)
                acc[mb][nb] = __builtin_amdgcn_mfma_f32_16x16x32_bf16(af[mb], bf[nb], acc[mb][nb], 0, 0, 0);
        __syncthreads();   // protect LDS before next stage
    }

    // epilogue: logits + bias, store, per-row partial (max, sumexp) over this wave's 64 cols
    float bg[4];
    for (int nb = 0; nb < 4; ++nb) bg[nb] = b_gen[n0 + wn + nb * 16 + lr];
    int chunk = nIdx * 2 + (wid & 1);     // 500 chunks of 64 cols
    for (int mb = 0; mb < 4; ++mb) {
        for (int r = 0; r < 4; ++r) {
            int row = m0 + wm + mb * 16 + lg * 4 + r;
            float v[4];
            float mx = -INFINITY;
            for (int nb = 0; nb < 4; ++nb) {
                v[nb] = acc[mb][nb][r] + bg[nb];
                mx = fmaxf(mx, v[nb]);
                out[(size_t)row * VOC + n0 + wn + nb * 16 + lr] = v[nb];
            }
            for (int k = 8; k >= 1; k >>= 1) mx = fmaxf(mx, __shfl_xor(mx, k, 16));
            float se = 0.f;
            for (int nb = 0; nb < 4; ++nb) se += __expf(v[nb] - mx);
            for (int k = 8; k >= 1; k >>= 1) se += __shfl_xor(se, k, 16);
            if (lr == 0) {
                float2 pv; pv.x = mx; pv.y = se;
                *(float2*)(partials + ((size_t)row * 500 + chunk) * 2) = pv;
            }
        }
    }
}

// ---------------- combine per-chunk partials into row M,S ---------------------------
__global__ __launch_bounds__(256) void reduce_kernel(const float* __restrict__ partials,
                                                     float* __restrict__ Ms,
                                                     float* __restrict__ Ss) {
    int wid = threadIdx.x >> 6, lane = threadIdx.x & 63;
    int row = blockIdx.x * 4 + wid;
    float m = -INFINITY, s = 0.f;
    for (int c = lane; c < 500; c += 64) {
        float2 p = *(const float2*)(partials + ((size_t)row * 500 + c) * 2);
        float nm = fmaxf(m, p.x);
        s = s * __expf(m - nm) + p.y * __expf(p.x - nm);
        m = nm;
    }
    for (int k = 32; k >= 1; k >>= 1) {
        float om = __shfl_xor(m, k, 64), os = __shfl_xor(s, k, 64);
        float nm = fmaxf(m, om);
        s = s * __expf(m - nm) + os * __expf(om - nm);
        m = nm;
    }
    if (lane == 0) { Ms[row] = m; Ss[row] = s; }
}

// ---------------- finalize: softmax scale, scatter-add p_c, log ---------------------
__global__ __launch_bounds__(256) void finalize_kernel(const int* __restrict__ src,
                                                       const float* __restrict__ p_c,
                                                       const float* __restrict__ cp,
                                                       const float* __restrict__ Ms,
                                                       const float* __restrict__ Ss,
                                                       float* __restrict__ out) {
    int row = blockIdx.y;
    int c0 = blockIdx.x * 1280;
    int b = row & (BSZ - 1);
    __shared__ float addv[1280];
    int tid = threadIdx.x;
    for (int i = tid; i < 1280; i += 256) addv[i] = 0.f;
    __syncthreads();
    if (tid < SLEN) {
        int v = src[b * SLEN + tid];
        if (v >= c0 && v < c0 + 1280) {
            atomicAdd(&addv[v - c0], p_c[row * SLEN + tid]);
        }
    }
    __syncthreads();
    float M = Ms[row];
    float g = (1.f - cp[row]) / Ss[row];
    size_t base = (size_t)row * VOC;
    for (int i = 0; i < 5; ++i) {
        int col = c0 + i * 256 + tid;
        float L = out[base + col];
        float p = __expf(L - M) * g + addv[i * 256 + tid];
        out[base + col] = __logf(p) + C_CONST_F;
    }
}

extern "C" void kernel_launch(void* const* d_in, const int* in_sizes, int n_in,
                              void* d_out, int out_size, void* d_ws, size_t ws_size,
                              hipStream_t stream) {
    const float* hidden  = (const float*)d_in[0];
    const float* context = (const float*)d_in[1];
    const int*   src     = (const int*)d_in[2];
    const float* W_gen   = (const float*)d_in[3];
    const float* b_gen   = (const float*)d_in[4];
    const float* w_copy  = (const float*)d_in[5];
    const float* b_copy  = (const float*)d_in[6];
    float* out = (float*)d_out;
    char* ws = (char*)d_ws;

    float*  cp       = (float*)(ws);                    // 2048 f32
    float*  p_c      = (float*)(ws + 8192);             // 2048*64 f32 = 512KB
    float*  Ms       = (float*)(ws + 532480);           // 2048 f32
    float*  Ss       = (float*)(ws + 540672);           // 2048 f32
    float*  partials = (float*)(ws + 548864);           // 2048*500*2 f32 = 8.192MB
    ushort* Abf      = (ushort*)(ws + 8740864);         // 2048*1024 bf16 = 4MB
    ushort* Wbf      = (ushort*)(ws + 12935168);        // 32000*1024 bf16 = 65.5MB
    // total ws use: ~78.5MB

    gate_kernel<<<NROW / 4, 256, 0, stream>>>(hidden, w_copy, b_copy, cp);
    attn_kernel<<<NROW, 256, 0, stream>>>(hidden, context, src, cp, p_c);
    cvt_kernel<<<(NROW * HS / 4) / 256, 256, 0, stream>>>(hidden, Abf, NROW * HS / 4);
    cvt_kernel<<<(VOC * HS / 4) / 256, 256, 0, stream>>>(W_gen, Wbf, VOC * HS / 4);
    gemm_kernel<<<(NROW / 128) * (VOC / 128), 256, 0, stream>>>(Abf, Wbf, b_gen, out, partials);
    reduce_kernel<<<NROW / 4, 256, 0, stream>>>(partials, Ms, Ss);
    dim3 fgrid(VOC / 1280, NROW);
    finalize_kernel<<<fgrid, 256, 0, stream>>>(src, p_c, cp, Ms, Ss, out);
}